// Round 4
// baseline (398.340 us; speedup 1.0000x reference)
//
#include <hip/hip_runtime.h>

// FastFFN: hierarchical-gated 8-leaf GLU MLP.
//   mixture[t][l] = cn[l>>2]*cn[l>>1]*cn[l]
//   H[t][l*512+h] = (x.w1a + b1a)*(x.w1b + b1b)*mixture   (bf16)
//   Y = H @ concat(w2) + sum_l mixture_l * b2_l           (fp32)
// R4: m97-shape GEMMs (128x128 tile, 256 thr, 2 blocks/CU TLP) + 2-slot dbuf
// with stage-at-top (full-tile prefetch slack), ONE barrier per tile,
// T2 LDS swizzle (0-conflict), T5 setprio, T1 XCD chunking.

typedef unsigned short u16;
typedef __attribute__((ext_vector_type(8))) short bf16x8;
typedef __attribute__((ext_vector_type(8))) unsigned short u16x8;
typedef __attribute__((ext_vector_type(4))) float f32x4;

__device__ __forceinline__ u16 f2bf(float f) {
  unsigned int u = __builtin_bit_cast(unsigned int, f);
  u += 0x7FFFu + ((u >> 16) & 1u);  // RNE
  return (u16)(u >> 16);
}

__device__ __forceinline__ void gload16(const void* g, void* l) {
  __builtin_amdgcn_global_load_lds(
      (const __attribute__((address_space(1))) unsigned int*)g,
      (__attribute__((address_space(3))) unsigned int*)l, 16, 0, 0);
}

__device__ __forceinline__ f32x4 MFMA(bf16x8 a, bf16x8 b, f32x4 c) {
  return __builtin_amdgcn_mfma_f32_16x16x32_bf16(a, b, c, 0, 0, 0);
}

#define BARX()                              \
  do {                                      \
    __builtin_amdgcn_sched_barrier(0);      \
    __builtin_amdgcn_s_barrier();           \
    __builtin_amdgcn_sched_barrier(0);      \
  } while (0)

#define VMC0()                                          \
  do {                                                  \
    __builtin_amdgcn_sched_barrier(0);                  \
    asm volatile("s_waitcnt vmcnt(0)" ::: "memory");    \
    __builtin_amdgcn_sched_barrier(0);                  \
  } while (0)

// ---------------- gate: mixture (8192 x 8) ----------------
__global__ void k_gate(const float* __restrict__ x, const float* __restrict__ nk,
                       const float* __restrict__ nb, float* __restrict__ mix) {
  int token = blockIdx.x * 4 + (threadIdx.x >> 6);
  int lane = threadIdx.x & 63;
  const float* xr = x + (size_t)token * 1024;
  float a0 = 0.f, a1 = 0.f, a2 = 0.f, a3 = 0.f;
#pragma unroll
  for (int j = 0; j < 16; ++j) {
    int d = lane + j * 64;
    float xv = xr[d];
    const float* nkd = nk + d * 7;
    a0 = fmaf(xv, nkd[0], a0);
    a1 = fmaf(xv, nkd[1], a1);
    a2 = fmaf(xv, nkd[2], a2);
    a3 = fmaf(xv, nkd[3], a3);
  }
#pragma unroll
  for (int off = 32; off >= 1; off >>= 1) {
    a0 += __shfl_xor(a0, off);
    a1 += __shfl_xor(a1, off);
    a2 += __shfl_xor(a2, off);
    a3 += __shfl_xor(a3, off);
  }
  if (lane == 0) {
    float v[4] = {a0 + nb[0], a1 + nb[1], a2 + nb[2], a3 + nb[3]};
    float cn[8];
#pragma unroll
    for (int i = 0; i < 4; ++i) {
      float s = 1.f / (1.f + expf(-v[i]));
      cn[2 * i] = s;
      cn[2 * i + 1] = 1.f - s;
    }
    float* mr = mix + (size_t)token * 8;
#pragma unroll
    for (int l = 0; l < 8; ++l) mr[l] = cn[l >> 2] * cn[l >> 1] * cn[l];
  }
}

// ---------------- cast x -> bf16 ----------------
__global__ void k_cast_x(const float* __restrict__ x, u16* __restrict__ xb) {
  size_t i = (size_t)blockIdx.x * blockDim.x + threadIdx.x;  // 8 elems each
  const float4* p = (const float4*)x + i * 2;
  float4 v0 = p[0], v1 = p[1];
  u16x8 o;
  o[0] = f2bf(v0.x); o[1] = f2bf(v0.y); o[2] = f2bf(v0.z); o[3] = f2bf(v0.w);
  o[4] = f2bf(v1.x); o[5] = f2bf(v1.y); o[6] = f2bf(v1.z); o[7] = f2bf(v1.w);
  *((u16x8*)xb + i) = o;
}

// ------------- batched transpose+cast: out[(c),(r)] = in[l][r][c] -------------
__global__ void k_transpose_cast(const float* __restrict__ in, u16* __restrict__ out,
                                 int R, int C, long out_rstride, long leaf_base) {
  __shared__ float tile[32][33];
  int l = blockIdx.z;
  int c0 = blockIdx.x * 32, r0 = blockIdx.y * 32;
  const float* inl = in + (size_t)l * R * C;
  int tc = threadIdx.x & 31, tr = threadIdx.x >> 5;  // 0..7
#pragma unroll
  for (int i = 0; i < 4; ++i) {
    int r = tr + i * 8;
    tile[r][tc] = inl[(size_t)(r0 + r) * C + c0 + tc];
  }
  __syncthreads();
  u16* outl = out + (size_t)l * leaf_base;
#pragma unroll
  for (int i = 0; i < 4; ++i) {
    int c = tr + i * 8;
    outl[(size_t)(c0 + c) * out_rstride + r0 + tc] = f2bf(tile[tc][c]);
  }
}

// ---------------- GEMM1: GLU, H = (X@Wa+b1a)*(X@Wb+b1b)*mix ----------------
// X: 8192x1024 bf16 rm; Wa/Wb: 4096x1024 bf16 (NxK); H: 8192x4096 bf16
// grid 2048 (XCD-chunked: bn 4-per-XCD, bm fast), 256 thr, BK=32, NT=32.
__global__ __launch_bounds__(256, 2) void k_glu_gemm(
    const u16* __restrict__ Xb, const u16* __restrict__ Wa, const u16* __restrict__ Wb,
    const float* __restrict__ b1a, const float* __restrict__ b1b,
    const float* __restrict__ mix, u16* __restrict__ H) {
  constexpr int K = 1024, NT = 32;
  __shared__ u16 sA[2][4096];
  __shared__ u16 sBa[2][4096];
  __shared__ u16 sBb[2][4096];
  const int tid = threadIdx.x;
  const int logical = (blockIdx.x & 7) * 256 + (blockIdx.x >> 3);
  const int bn = logical >> 6, bm = logical & 63;
  const int m0 = bm * 128, n0 = bn * 128;
  const int wid = tid >> 6, lane = tid & 63;
  const int wm = (wid >> 1) * 64, wn = (wid & 1) * 64;
  const int fr = lane & 15, fk = lane >> 4;

  // staging: chunk c (16B) -> LDS linear c*16B; row = c>>2, LDS slot = c&3,
  // global source slot = (c&3) ^ ((row>>1)&3)   (involution; read applies same)
  const int c0_ = tid, c1_ = tid + 256;
  const int r0_ = c0_ >> 2, s0_ = ((c0_ & 3) ^ ((r0_ >> 1) & 3)) * 8;
  const int r1_ = c1_ >> 2, s1_ = ((c1_ & 3) ^ ((r1_ >> 1) & 3)) * 8;

#define STG1(v)                                                               \
  do {                                                                        \
    const int kb = (v) * 32;                                                  \
    gload16(&Xb[(size_t)(m0 + r0_) * K + kb + s0_], &sA[(v) & 1][c0_ * 8]);   \
    gload16(&Xb[(size_t)(m0 + r1_) * K + kb + s1_], &sA[(v) & 1][c1_ * 8]);   \
    gload16(&Wa[(size_t)(n0 + r0_) * K + kb + s0_], &sBa[(v) & 1][c0_ * 8]);  \
    gload16(&Wa[(size_t)(n0 + r1_) * K + kb + s1_], &sBa[(v) & 1][c1_ * 8]);  \
    gload16(&Wb[(size_t)(n0 + r0_) * K + kb + s0_], &sBb[(v) & 1][c0_ * 8]);  \
    gload16(&Wb[(size_t)(n0 + r1_) * K + kb + s1_], &sBb[(v) & 1][c1_ * 8]);  \
  } while (0)

  f32x4 accA[4][4], accB[4][4];
#pragma unroll
  for (int i = 0; i < 4; ++i)
#pragma unroll
    for (int j = 0; j < 4; ++j) {
      accA[i][j] = (f32x4)0.0f;
      accB[i][j] = (f32x4)0.0f;
    }

  // frag read slot: rows are wm/wn + i*16 + fr (base mult of 16) ->
  // ((row>>1)&3) == ((fr>>1)&3), lane-constant.
  const int slot_ = (fk ^ ((fr >> 1) & 3)) * 8;

  STG1(0);
  VMC0();
  BARX();
  for (int u = 0; u < NT; ++u) {
    if (u + 1 < NT) STG1(u + 1);            // full-tile prefetch slack
    __builtin_amdgcn_sched_barrier(0);      // pin stage issue before reads
    const u16* A_ = sA[u & 1];
    const u16* Ba_ = sBa[u & 1];
    const u16* Bb_ = sBb[u & 1];
    bf16x8 a_[4], ba_[4], bb_[4];
#pragma unroll
    for (int i = 0; i < 4; ++i) {
      a_[i]  = *(const bf16x8*)&A_[(wm + i * 16 + fr) * 32 + slot_];
      ba_[i] = *(const bf16x8*)&Ba_[(wn + i * 16 + fr) * 32 + slot_];
      bb_[i] = *(const bf16x8*)&Bb_[(wn + i * 16 + fr) * 32 + slot_];
    }
    __builtin_amdgcn_s_setprio(1);
#pragma unroll
    for (int i = 0; i < 4; ++i)
#pragma unroll
      for (int j = 0; j < 4; ++j) {
        accA[i][j] = MFMA(a_[i], ba_[j], accA[i][j]);
        accB[i][j] = MFMA(a_[i], bb_[j], accB[i][j]);
      }
    __builtin_amdgcn_s_setprio(0);
    VMC0();   // next tile landed; slack was reads+MFMAs (+TLP from 2 blocks/CU)
    BARX();
  }
#undef STG1

  const int leaf = n0 >> 9;
  const float* b1al = b1a + (leaf << 9);
  const float* b1bl = b1b + (leaf << 9);
#pragma unroll
  for (int mf = 0; mf < 4; ++mf)
#pragma unroll
    for (int r = 0; r < 4; ++r) {
      int row = m0 + wm + mf * 16 + fk * 4 + r;
      float mv = mix[(size_t)row * 8 + leaf];
#pragma unroll
      for (int nf = 0; nf < 4; ++nf) {
        int col = n0 + wn + nf * 16 + fr;
        int hc = col & 511;
        float va = accA[mf][nf][r] + b1al[hc];
        float vb = accB[mf][nf][r] + b1bl[hc];
        H[(size_t)row * 4096 + col] = f2bf(va * vb * mv);
      }
    }
}

// ---------------- GEMM2: Y = H @ W2cat + sum_l mix_l*b2_l ----------------
// H: 8192x4096 bf16; W2T: 1024x4096 bf16 (NxK); out: 8192x1024 fp32
// grid 512 (XCD-chunked, bn fast), 256 thr, BK=64, NT=64.
__global__ __launch_bounds__(256, 2) void k_gemm2(
    const u16* __restrict__ Hm, const u16* __restrict__ W2T,
    const float* __restrict__ b2, const float* __restrict__ mix,
    float* __restrict__ out) {
  constexpr int K = 4096, NT = 64;
  __shared__ u16 sA[2][8192];
  __shared__ u16 sB[2][8192];
  const int tid = threadIdx.x;
  const int logical = (blockIdx.x & 7) * 64 + (blockIdx.x >> 3);
  const int bn = logical & 7, bm = logical >> 3;
  const int m0 = bm * 128, n0 = bn * 128;
  const int wid = tid >> 6, lane = tid & 63;
  const int wm = (wid >> 1) * 64, wn = (wid & 1) * 64;
  const int fr = lane & 15, fk = lane >> 4;

  // staging: chunk c = j*256+tid (j=0..3); row = c>>3, LDS slot = c&7,
  // global source slot = (c&7) ^ (row&7)
  int rs_[4], ss_[4];
#pragma unroll
  for (int j = 0; j < 4; ++j) {
    int c = j * 256 + tid;
    rs_[j] = c >> 3;
    ss_[j] = ((c & 7) ^ (rs_[j] & 7)) * 8;
  }

#define STG2(v)                                                                   \
  do {                                                                            \
    const int kb = (v) * 64;                                                      \
    _Pragma("unroll")                                                             \
    for (int j = 0; j < 4; ++j) {                                                 \
      gload16(&Hm[(size_t)(m0 + rs_[j]) * K + kb + ss_[j]],                       \
              &sA[(v) & 1][(j * 256 + tid) * 8]);                                 \
      gload16(&W2T[(size_t)(n0 + rs_[j]) * K + kb + ss_[j]],                      \
              &sB[(v) & 1][(j * 256 + tid) * 8]);                                 \
    }                                                                             \
  } while (0)

  f32x4 acc[4][4];
#pragma unroll
  for (int i = 0; i < 4; ++i)
#pragma unroll
    for (int j = 0; j < 4; ++j) acc[i][j] = (f32x4)0.0f;

  // frag read slots for ksteps s=0,1: ((s*4+fk) ^ (row&7)); row&7 == fr&7
  const int sw0 = ((fk) ^ (fr & 7)) * 8;
  const int sw1 = ((4 + fk) ^ (fr & 7)) * 8;

  STG2(0);
  VMC0();
  BARX();
  for (int u = 0; u < NT; ++u) {
    if (u + 1 < NT) STG2(u + 1);            // full-tile prefetch slack
    __builtin_amdgcn_sched_barrier(0);
    const u16* A_ = sA[u & 1];
    const u16* B_ = sB[u & 1];
    bf16x8 a_[4][2], b_[4][2];
#pragma unroll
    for (int i = 0; i < 4; ++i) {
      int ra = (wm + i * 16 + fr) * 64;
      int rb = (wn + i * 16 + fr) * 64;
      a_[i][0] = *(const bf16x8*)&A_[ra + sw0];
      a_[i][1] = *(const bf16x8*)&A_[ra + sw1];
      b_[i][0] = *(const bf16x8*)&B_[rb + sw0];
      b_[i][1] = *(const bf16x8*)&B_[rb + sw1];
    }
    __builtin_amdgcn_s_setprio(1);
#pragma unroll
    for (int i = 0; i < 4; ++i)
#pragma unroll
      for (int j = 0; j < 4; ++j) {
        acc[i][j] = MFMA(a_[i][0], b_[j][0], acc[i][j]);
        acc[i][j] = MFMA(a_[i][1], b_[j][1], acc[i][j]);
      }
    __builtin_amdgcn_s_setprio(0);
    VMC0();
    BARX();
  }
#undef STG2

#pragma unroll
  for (int nf = 0; nf < 4; ++nf) {
    int col = n0 + wn + nf * 16 + fr;
    float bc[8];
#pragma unroll
    for (int l = 0; l < 8; ++l) bc[l] = b2[l * 1024 + col];
#pragma unroll
    for (int mf = 0; mf < 4; ++mf)
#pragma unroll
      for (int r = 0; r < 4; ++r) {
        int row = m0 + wm + mf * 16 + fk * 4 + r;
        const float* mr = mix + (size_t)row * 8;
        float bias = 0.f;
#pragma unroll
        for (int l = 0; l < 8; ++l) bias = fmaf(mr[l], bc[l], bias);
        out[(size_t)row * 1024 + col] = acc[mf][nf][r] + bias;
      }
  }
}

extern "C" void kernel_launch(void* const* d_in, const int* in_sizes, int n_in,
                              void* d_out, int out_size, void* d_ws, size_t ws_size,
                              hipStream_t stream) {
  const float* x   = (const float*)d_in[0];
  const float* nk  = (const float*)d_in[1];
  const float* nb  = (const float*)d_in[2];
  const float* w1a = (const float*)d_in[3];
  const float* w1b = (const float*)d_in[4];
  const float* b1a = (const float*)d_in[5];
  const float* b1b = (const float*)d_in[6];
  const float* w2  = (const float*)d_in[7];
  const float* b2  = (const float*)d_in[8];
  float* out = (float*)d_out;

  char* ws = (char*)d_ws;
  // layout: mixture | Xbf | W1aT | W1bT | W2T | H   (total ~109.3 MB)
  float* mix = (float*)ws;                                   // 262144 B
  u16* Xb  = (u16*)(ws + 262144);                            // 16777216 B
  u16* WaT = (u16*)(ws + 262144 + 16777216);                 // 8388608 B
  u16* WbT = (u16*)(ws + 262144 + 16777216 + 8388608);       // 8388608 B
  u16* W2T = (u16*)(ws + 262144 + 16777216 + 2 * 8388608);   // 8388608 B
  u16* Hs  = (u16*)(ws + 262144 + 16777216 + 3 * 8388608);   // 67108864 B

  k_gate<<<2048, 256, 0, stream>>>(x, nk, nb, mix);
  k_cast_x<<<4096, 256, 0, stream>>>(x, Xb);
  // w1a[l][d][h] -> WaT[(l*512+h)*1024 + d]
  k_transpose_cast<<<dim3(16, 32, 8), 256, 0, stream>>>(w1a, WaT, 1024, 512, 1024L, 512L * 1024L);
  k_transpose_cast<<<dim3(16, 32, 8), 256, 0, stream>>>(w1b, WbT, 1024, 512, 1024L, 512L * 1024L);
  // w2[l][h][dout] -> W2T[dout*4096 + l*512 + h]
  k_transpose_cast<<<dim3(32, 16, 8), 256, 0, stream>>>(w2, W2T, 512, 1024, 4096L, 512L);
  k_glu_gemm<<<2048, 256, 0, stream>>>(Xb, WaT, WbT, b1a, b1b, mix, Hs);
  k_gemm2<<<512, 256, 0, stream>>>(Hs, W2T, b2, mix, out);
}